// Round 1
// baseline (216.277 us; speedup 1.0000x reference)
//
#include <hip/hip_runtime.h>

#define NB 4
#define SLQ 256
#define SLK 256
#define DD 768

// 2*log2(e): folded into q/k projections so tanh's exp(2x) becomes exp2(qs+ks)
#define TWO_LOG2E 2.8853900817779268f
#define LOG2E 1.4426950408889634f

__device__ __forceinline__ float fexp2(float x) { return __builtin_amdgcn_exp2f(x); }
__device__ __forceinline__ float frcp(float x) { return __builtin_amdgcn_rcpf(x); }

// ---------------- QKV projection: C = (A @ W + bias) * scale ----------------
// A: [1024 x 768] row-major, W: [768 x 768] row-major ([in,out]), bias: [768]
// 64x64 tile, BK=16, 256 threads, 4x4 micro-tile per thread.
__global__ __launch_bounds__(256) void qkv_gemm_kernel(
    const float* __restrict__ query, const float* __restrict__ key_in,
    const float* __restrict__ value, const float* __restrict__ Wq,
    const float* __restrict__ bq, const float* __restrict__ Wk,
    const float* __restrict__ bk, const float* __restrict__ Wv,
    const float* __restrict__ bv, float* __restrict__ qs,
    float* __restrict__ ks, float* __restrict__ vs)
{
    const int z = blockIdx.z;
    const float* A = (z == 0) ? query : (z == 1) ? key_in : value;
    const float* W = (z == 0) ? Wq : (z == 1) ? Wk : Wv;
    const float* bias = (z == 0) ? bq : (z == 1) ? bk : bv;
    float* C = (z == 0) ? qs : (z == 1) ? ks : vs;
    const float scale = (z == 2) ? 1.0f : TWO_LOG2E;

    __shared__ __align__(16) float As[16][64]; // [k][m]
    __shared__ __align__(16) float Bs[16][64]; // [k][n]

    const int tid = threadIdx.x;
    const int tx = tid & 15;        // n quad
    const int ty = tid >> 4;        // m quad
    const int row0 = blockIdx.y * 64;
    const int col0 = blockIdx.x * 64;
    const int a_r = tid >> 2;       // 0..63
    const int a_k = (tid & 3) << 2; // 0,4,8,12
    const int b_r = tid >> 4;       // 0..15
    const int b_c = (tid & 15) << 2;

    float acc[4][4] = {};

    for (int k0 = 0; k0 < DD; k0 += 16) {
        float4 av = *(const float4*)&A[(size_t)(row0 + a_r) * DD + k0 + a_k];
        float4 wv = *(const float4*)&W[(size_t)(k0 + b_r) * DD + col0 + b_c];
        __syncthreads();
        As[a_k + 0][a_r] = av.x;
        As[a_k + 1][a_r] = av.y;
        As[a_k + 2][a_r] = av.z;
        As[a_k + 3][a_r] = av.w;
        *(float4*)&Bs[b_r][b_c] = wv;
        __syncthreads();
#pragma unroll
        for (int kk = 0; kk < 16; ++kk) {
            float4 a = *(const float4*)&As[kk][ty << 2];
            float4 b = *(const float4*)&Bs[kk][tx << 2];
            acc[0][0] = fmaf(a.x, b.x, acc[0][0]);
            acc[0][1] = fmaf(a.x, b.y, acc[0][1]);
            acc[0][2] = fmaf(a.x, b.z, acc[0][2]);
            acc[0][3] = fmaf(a.x, b.w, acc[0][3]);
            acc[1][0] = fmaf(a.y, b.x, acc[1][0]);
            acc[1][1] = fmaf(a.y, b.y, acc[1][1]);
            acc[1][2] = fmaf(a.y, b.z, acc[1][2]);
            acc[1][3] = fmaf(a.y, b.w, acc[1][3]);
            acc[2][0] = fmaf(a.z, b.x, acc[2][0]);
            acc[2][1] = fmaf(a.z, b.y, acc[2][1]);
            acc[2][2] = fmaf(a.z, b.z, acc[2][2]);
            acc[2][3] = fmaf(a.z, b.w, acc[2][3]);
            acc[3][0] = fmaf(a.w, b.x, acc[3][0]);
            acc[3][1] = fmaf(a.w, b.y, acc[3][1]);
            acc[3][2] = fmaf(a.w, b.z, acc[3][2]);
            acc[3][3] = fmaf(a.w, b.w, acc[3][3]);
        }
    }

    float4 b4 = *(const float4*)&bias[col0 + (tx << 2)];
#pragma unroll
    for (int i = 0; i < 4; ++i) {
        float4 o;
        o.x = (acc[i][0] + b4.x) * scale;
        o.y = (acc[i][1] + b4.y) * scale;
        o.z = (acc[i][2] + b4.z) * scale;
        o.w = (acc[i][3] + b4.w) * scale;
        *(float4*)&C[(size_t)(row0 + (ty << 2) + i) * DD + col0 + (tx << 2)] = o;
    }
}

// ---------------- Scores: logits[b,q,k] = -2 * sum_d Ws_d / (1 + exp2(qs+ks)) ----------------
// qs,ks are pre-scaled by 2*log2(e). One thread per (q,k); 4q x 64k per block.
__global__ __launch_bounds__(256) void scores_kernel(
    const float* __restrict__ qs, const float* __restrict__ ks,
    const float* __restrict__ Ws, float* __restrict__ logits)
{
    const int b = blockIdx.z;
    const int q0 = blockIdx.y * 4;
    const int k0 = blockIdx.x * 64;
    const int tid = threadIdx.x;
    const int kl = tid & 63;   // lane within wave -> k
    const int ql = tid >> 6;   // wave -> q (wave-uniform)

    __shared__ float q_l[4][65];
    __shared__ float k_l[64][65];
    __shared__ float w_l[64];

    const float* qrow = qs + (size_t)(b * SLQ + q0) * DD;
    const float* krow = ks + (size_t)(b * SLK + k0) * DD;

    float acc0 = 0.f, acc1 = 0.f, acc2 = 0.f, acc3 = 0.f;

    for (int d0 = 0; d0 < DD; d0 += 64) {
        __syncthreads();
        // stage 64x64 K-chunk (each thread 4 float4s)
#pragma unroll
        for (int j = 0; j < 4; ++j) {
            int fidx = tid + j * 256;        // float4 index 0..1023
            int r = fidx >> 4;
            int c = (fidx & 15) << 2;
            float4 v = *(const float4*)&krow[(size_t)r * DD + d0 + c];
            k_l[r][c + 0] = v.x;
            k_l[r][c + 1] = v.y;
            k_l[r][c + 2] = v.z;
            k_l[r][c + 3] = v.w;
        }
        if (tid < 64) {
            int r = tid >> 4;
            int c = (tid & 15) << 2;
            float4 v = *(const float4*)&qrow[(size_t)r * DD + d0 + c];
            q_l[r][c + 0] = v.x;
            q_l[r][c + 1] = v.y;
            q_l[r][c + 2] = v.z;
            q_l[r][c + 3] = v.w;
            w_l[tid] = Ws[d0 + tid];
        }
        __syncthreads();
#pragma unroll
        for (int d = 0; d < 64; d += 4) {
            acc0 = fmaf(w_l[d + 0], frcp(1.0f + fexp2(q_l[ql][d + 0] + k_l[kl][d + 0])), acc0);
            acc1 = fmaf(w_l[d + 1], frcp(1.0f + fexp2(q_l[ql][d + 1] + k_l[kl][d + 1])), acc1);
            acc2 = fmaf(w_l[d + 2], frcp(1.0f + fexp2(q_l[ql][d + 2] + k_l[kl][d + 2])), acc2);
            acc3 = fmaf(w_l[d + 3], frcp(1.0f + fexp2(q_l[ql][d + 3] + k_l[kl][d + 3])), acc3);
        }
    }

    float logit = -2.0f * ((acc0 + acc1) + (acc2 + acc3));
    logits[(size_t)(b * SLQ + q0 + ql) * SLK + k0 + kl] = logit;
}

// ---------------- Softmax over k (in-place on logits buffer) ----------------
// One wave per row of 256; 4 rows per block.
__global__ __launch_bounds__(256) void softmax_kernel(float* __restrict__ attn)
{
    const int lane = threadIdx.x & 63;
    const int wave = threadIdx.x >> 6;
    const int row = blockIdx.x * 4 + wave; // 0..1023
    float* rp = attn + (size_t)row * SLK;

    float4 x = *(const float4*)&rp[lane << 2];
    float m = fmaxf(fmaxf(x.x, x.y), fmaxf(x.z, x.w));
#pragma unroll
    for (int off = 32; off; off >>= 1) m = fmaxf(m, __shfl_xor(m, off, 64));

    float e0 = fexp2((x.x - m) * LOG2E);
    float e1 = fexp2((x.y - m) * LOG2E);
    float e2 = fexp2((x.z - m) * LOG2E);
    float e3 = fexp2((x.w - m) * LOG2E);
    float s = (e0 + e1) + (e2 + e3);
#pragma unroll
    for (int off = 32; off; off >>= 1) s += __shfl_xor(s, off, 64);

    float inv = 1.0f / s;
    float4 o;
    o.x = e0 * inv;
    o.y = e1 * inv;
    o.z = e2 * inv;
    o.w = e3 * inv;
    *(float4*)&rp[lane << 2] = o;
}

// ---------------- Attended: out[b] = attn[b] (256x256) @ v[b] (256x768) ----------------
__global__ __launch_bounds__(256) void attended_gemm_kernel(
    const float* __restrict__ attn, const float* __restrict__ vs,
    float* __restrict__ out)
{
    const int b = blockIdx.z;
    const float* A = attn + (size_t)b * SLQ * SLK;
    const float* Bm = vs + (size_t)b * SLK * DD;
    float* C = out + (size_t)b * SLQ * DD;

    __shared__ __align__(16) float As[16][64];
    __shared__ __align__(16) float Bs[16][64];

    const int tid = threadIdx.x;
    const int tx = tid & 15;
    const int ty = tid >> 4;
    const int row0 = blockIdx.y * 64;  // 0..192
    const int col0 = blockIdx.x * 64;  // 0..704
    const int a_r = tid >> 2;
    const int a_k = (tid & 3) << 2;
    const int b_r = tid >> 4;
    const int b_c = (tid & 15) << 2;

    float acc[4][4] = {};

    for (int k0 = 0; k0 < SLK; k0 += 16) {
        float4 av = *(const float4*)&A[(size_t)(row0 + a_r) * SLK + k0 + a_k];
        float4 wv = *(const float4*)&Bm[(size_t)(k0 + b_r) * DD + col0 + b_c];
        __syncthreads();
        As[a_k + 0][a_r] = av.x;
        As[a_k + 1][a_r] = av.y;
        As[a_k + 2][a_r] = av.z;
        As[a_k + 3][a_r] = av.w;
        *(float4*)&Bs[b_r][b_c] = wv;
        __syncthreads();
#pragma unroll
        for (int kk = 0; kk < 16; ++kk) {
            float4 a = *(const float4*)&As[kk][ty << 2];
            float4 b = *(const float4*)&Bs[kk][tx << 2];
            acc[0][0] = fmaf(a.x, b.x, acc[0][0]);
            acc[0][1] = fmaf(a.x, b.y, acc[0][1]);
            acc[0][2] = fmaf(a.x, b.z, acc[0][2]);
            acc[0][3] = fmaf(a.x, b.w, acc[0][3]);
            acc[1][0] = fmaf(a.y, b.x, acc[1][0]);
            acc[1][1] = fmaf(a.y, b.y, acc[1][1]);
            acc[1][2] = fmaf(a.y, b.z, acc[1][2]);
            acc[1][3] = fmaf(a.y, b.w, acc[1][3]);
            acc[2][0] = fmaf(a.z, b.x, acc[2][0]);
            acc[2][1] = fmaf(a.z, b.y, acc[2][1]);
            acc[2][2] = fmaf(a.z, b.z, acc[2][2]);
            acc[2][3] = fmaf(a.z, b.w, acc[2][3]);
            acc[3][0] = fmaf(a.w, b.x, acc[3][0]);
            acc[3][1] = fmaf(a.w, b.y, acc[3][1]);
            acc[3][2] = fmaf(a.w, b.z, acc[3][2]);
            acc[3][3] = fmaf(a.w, b.w, acc[3][3]);
        }
    }

#pragma unroll
    for (int i = 0; i < 4; ++i) {
        float4 o;
        o.x = acc[i][0];
        o.y = acc[i][1];
        o.z = acc[i][2];
        o.w = acc[i][3];
        *(float4*)&C[(size_t)(row0 + (ty << 2) + i) * DD + col0 + (tx << 2)] = o;
    }
}

extern "C" void kernel_launch(void* const* d_in, const int* in_sizes, int n_in,
                              void* d_out, int out_size, void* d_ws, size_t ws_size,
                              hipStream_t stream)
{
    (void)in_sizes; (void)n_in; (void)out_size; (void)ws_size;

    const float* query = (const float*)d_in[0];
    const float* key   = (const float*)d_in[1];
    const float* value = (const float*)d_in[2];
    const float* Wq = (const float*)d_in[3];
    const float* bq = (const float*)d_in[4];
    const float* Wk = (const float*)d_in[5];
    const float* bk = (const float*)d_in[6];
    const float* Wv = (const float*)d_in[7];
    const float* bv = (const float*)d_in[8];
    const float* Ws = (const float*)d_in[9];
    // d_in[10] (bs) is a softmax-invariant shift: unused.

    float* ws = (float*)d_ws;
    float* qs = ws;                       // [4,256,768] pre-scaled q
    float* ks = qs + NB * SLQ * DD;       // [4,256,768] pre-scaled k
    float* vs = ks + NB * SLK * DD;       // [4,256,768] v

    float* out = (float*)d_out;
    float* attended = out;                // [4,256,768]
    float* attnw = out + NB * SLQ * DD;   // [4,256,256]: logits, then softmax in-place

    qkv_gemm_kernel<<<dim3(DD / 64, (NB * SLQ) / 64, 3), 256, 0, stream>>>(
        query, key, value, Wq, bq, Wk, bk, Wv, bv, qs, ks, vs);
    scores_kernel<<<dim3(SLK / 64, SLQ / 4, NB), 256, 0, stream>>>(qs, ks, Ws, attnw);
    softmax_kernel<<<dim3((NB * SLQ) / 4), 256, 0, stream>>>(attnw);
    attended_gemm_kernel<<<dim3(DD / 64, SLQ / 64, NB), 256, 0, stream>>>(attnw, vs, attended);
}

// Round 2
// 190.899 us; speedup vs baseline: 1.1329x; 1.1329x over previous
//
#include <hip/hip_runtime.h>

#define NB 4
#define SLQ 256
#define SLK 256
#define DD 768

// 2*log2(e): folded into q/k projections; tanh(x) = 1 - 2/(1 + exp2((q+k)*2log2e))
// and exp2(q+k) factorizes into exp2(q)*exp2(k) computed once in the projection.
#define TWO_LOG2E 2.8853900817779268f
#define LOG2E 1.4426950408889634f

__device__ __forceinline__ float fexp2(float x) { return __builtin_amdgcn_exp2f(x); }
__device__ __forceinline__ float frcp(float x) { return __builtin_amdgcn_rcpf(x); }

// ---------------- QKV projection ----------------
// C = A @ W + bias ; for z<2 store exp2((..)*2log2e), for z==2 store raw.
// A: [1024 x 768], W: [768 x 768] ([in,out]), 64x64 tile, BK=16, 256 thr, 4x4 micro.
// Software prefetch: global loads for step k+1 issued before compute of step k.
__global__ __launch_bounds__(256) void qkv_gemm_kernel(
    const float* __restrict__ query, const float* __restrict__ key_in,
    const float* __restrict__ value, const float* __restrict__ Wq,
    const float* __restrict__ bq, const float* __restrict__ Wk,
    const float* __restrict__ bk, const float* __restrict__ Wv,
    const float* __restrict__ bv, float* __restrict__ eq,
    float* __restrict__ ek, float* __restrict__ vs)
{
    const int z = blockIdx.z;
    const float* A = (z == 0) ? query : (z == 1) ? key_in : value;
    const float* W = (z == 0) ? Wq : (z == 1) ? Wk : Wv;
    const float* bias = (z == 0) ? bq : (z == 1) ? bk : bv;
    float* C = (z == 0) ? eq : (z == 1) ? ek : vs;
    const bool do_exp = (z < 2);

    // stride 68: transpose-store banks (4*a_k + a_r) -> 2-way max (free);
    // float4 reads stay 16B-aligned (68 % 4 == 0).
    __shared__ __align__(16) float As[16][68]; // [k][m]
    __shared__ __align__(16) float Bs[16][64]; // [k][n]

    const int tid = threadIdx.x;
    const int tx = tid & 15;
    const int ty = tid >> 4;
    const int row0 = blockIdx.y * 64;
    const int col0 = blockIdx.x * 64;
    const int a_r = tid >> 2;
    const int a_k = (tid & 3) << 2;
    const int b_r = tid >> 4;
    const int b_c = (tid & 15) << 2;

    const float* Aptr = A + (size_t)(row0 + a_r) * DD + a_k;
    const float* Wptr = W + (size_t)b_r * DD + col0 + b_c;

    float4 av = *(const float4*)Aptr;
    float4 wv = *(const float4*)Wptr;

    float acc[4][4] = {};

    for (int k0 = 0; k0 < DD; k0 += 16) {
        __syncthreads();
        As[a_k + 0][a_r] = av.x;
        As[a_k + 1][a_r] = av.y;
        As[a_k + 2][a_r] = av.z;
        As[a_k + 3][a_r] = av.w;
        *(float4*)&Bs[b_r][b_c] = wv;
        __syncthreads();
        if (k0 + 16 < DD) {
            av = *(const float4*)(Aptr + k0 + 16);
            wv = *(const float4*)(Wptr + (size_t)(k0 + 16) * DD);
        }
#pragma unroll
        for (int kk = 0; kk < 16; ++kk) {
            float4 a = *(const float4*)&As[kk][ty << 2];
            float4 b = *(const float4*)&Bs[kk][tx << 2];
            acc[0][0] = fmaf(a.x, b.x, acc[0][0]);
            acc[0][1] = fmaf(a.x, b.y, acc[0][1]);
            acc[0][2] = fmaf(a.x, b.z, acc[0][2]);
            acc[0][3] = fmaf(a.x, b.w, acc[0][3]);
            acc[1][0] = fmaf(a.y, b.x, acc[1][0]);
            acc[1][1] = fmaf(a.y, b.y, acc[1][1]);
            acc[1][2] = fmaf(a.y, b.z, acc[1][2]);
            acc[1][3] = fmaf(a.y, b.w, acc[1][3]);
            acc[2][0] = fmaf(a.z, b.x, acc[2][0]);
            acc[2][1] = fmaf(a.z, b.y, acc[2][1]);
            acc[2][2] = fmaf(a.z, b.z, acc[2][2]);
            acc[2][3] = fmaf(a.z, b.w, acc[2][3]);
            acc[3][0] = fmaf(a.w, b.x, acc[3][0]);
            acc[3][1] = fmaf(a.w, b.y, acc[3][1]);
            acc[3][2] = fmaf(a.w, b.z, acc[3][2]);
            acc[3][3] = fmaf(a.w, b.w, acc[3][3]);
        }
    }

    float4 b4 = *(const float4*)&bias[col0 + (tx << 2)];
#pragma unroll
    for (int i = 0; i < 4; ++i) {
        float4 o;
        o.x = acc[i][0] + b4.x;
        o.y = acc[i][1] + b4.y;
        o.z = acc[i][2] + b4.z;
        o.w = acc[i][3] + b4.w;
        if (do_exp) {
            o.x = fexp2(o.x * TWO_LOG2E);
            o.y = fexp2(o.y * TWO_LOG2E);
            o.z = fexp2(o.z * TWO_LOG2E);
            o.w = fexp2(o.w * TWO_LOG2E);
        }
        *(float4*)&C[(size_t)(row0 + (ty << 2) + i) * DD + col0 + (tx << 2)] = o;
    }
}

// ---------------- Scores ----------------
// logits[b,q,k] = -2 * sum_d Ws_d * rcp(1 + Eq[q,d]*Ek[k,d])
// (softmax-invariant constants dropped). Block = 4 q x 64 k, 256 threads.
__global__ __launch_bounds__(256) void scores_kernel(
    const float* __restrict__ Eq, const float* __restrict__ Ek,
    const float* __restrict__ Ws, float* __restrict__ logits)
{
    const int b = blockIdx.z;
    const int q0 = blockIdx.y * 4;
    const int k0 = blockIdx.x * 64;
    const int tid = threadIdx.x;
    const int kl = tid & 63;   // lane -> k
    const int ql = tid >> 6;   // wave -> q (wave-uniform)

    __shared__ __align__(16) float k_l[64][68];
    __shared__ __align__(16) float q_l[4][68];
    __shared__ __align__(16) float w_l[68];

    const float* qrow = Eq + (size_t)(b * SLQ + q0) * DD;
    const float* krow = Ek + (size_t)(b * SLK + k0) * DD;

    // staging roles
    const int sr = tid >> 2;               // k row 0..63
    const int sc = (tid & 3) << 2;         // col base 0,4,8,12 (then +16i)
    const int qr = tid >> 4;               // q row (tid<64)
    const int qc = (tid & 15) << 2;
    const int wc = (tid - 64) << 2;        // (64<=tid<80)

    float4 pk0, pk1, pk2, pk3, pq, pw;
    {
        const float* kp = krow + (size_t)sr * DD + sc;
        pk0 = *(const float4*)(kp + 0);
        pk1 = *(const float4*)(kp + 16);
        pk2 = *(const float4*)(kp + 32);
        pk3 = *(const float4*)(kp + 48);
        if (tid < 64) pq = *(const float4*)(qrow + (size_t)qr * DD + qc);
        if (tid >= 64 && tid < 80) pw = *(const float4*)(Ws + wc);
    }

    float acc0 = 0.f, acc1 = 0.f, acc2 = 0.f, acc3 = 0.f;

    for (int c = 0; c < DD / 64; ++c) {
        __syncthreads();
        *(float4*)&k_l[sr][sc + 0]  = pk0;
        *(float4*)&k_l[sr][sc + 16] = pk1;
        *(float4*)&k_l[sr][sc + 32] = pk2;
        *(float4*)&k_l[sr][sc + 48] = pk3;
        if (tid < 64) *(float4*)&q_l[qr][qc] = pq;
        if (tid >= 64 && tid < 80) *(float4*)&w_l[wc] = pw;
        __syncthreads();
        if (c + 1 < DD / 64) {
            const int d0 = (c + 1) * 64;
            const float* kp = krow + (size_t)sr * DD + d0 + sc;
            pk0 = *(const float4*)(kp + 0);
            pk1 = *(const float4*)(kp + 16);
            pk2 = *(const float4*)(kp + 32);
            pk3 = *(const float4*)(kp + 48);
            if (tid < 64) pq = *(const float4*)(qrow + (size_t)qr * DD + d0 + qc);
            if (tid >= 64 && tid < 80) pw = *(const float4*)(Ws + d0 + wc);
        }
#pragma unroll
        for (int d = 0; d < 64; d += 4) {
            float4 e = *(const float4*)&k_l[kl][d];
            float4 g = *(const float4*)&q_l[ql][d];
            float4 w = *(const float4*)&w_l[d];
            acc0 = fmaf(w.x, frcp(fmaf(g.x, e.x, 1.0f)), acc0);
            acc1 = fmaf(w.y, frcp(fmaf(g.y, e.y, 1.0f)), acc1);
            acc2 = fmaf(w.z, frcp(fmaf(g.z, e.z, 1.0f)), acc2);
            acc3 = fmaf(w.w, frcp(fmaf(g.w, e.w, 1.0f)), acc3);
        }
    }

    float logit = -2.0f * ((acc0 + acc1) + (acc2 + acc3));
    logits[(size_t)(b * SLQ + q0 + ql) * SLK + k0 + kl] = logit;
}

// ---------------- Softmax over k (in-place) ----------------
__global__ __launch_bounds__(256) void softmax_kernel(float* __restrict__ attn)
{
    const int lane = threadIdx.x & 63;
    const int wave = threadIdx.x >> 6;
    const int row = blockIdx.x * 4 + wave;
    float* rp = attn + (size_t)row * SLK;

    float4 x = *(const float4*)&rp[lane << 2];
    float m = fmaxf(fmaxf(x.x, x.y), fmaxf(x.z, x.w));
#pragma unroll
    for (int off = 32; off; off >>= 1) m = fmaxf(m, __shfl_xor(m, off, 64));

    float e0 = fexp2((x.x - m) * LOG2E);
    float e1 = fexp2((x.y - m) * LOG2E);
    float e2 = fexp2((x.z - m) * LOG2E);
    float e3 = fexp2((x.w - m) * LOG2E);
    float s = (e0 + e1) + (e2 + e3);
#pragma unroll
    for (int off = 32; off; off >>= 1) s += __shfl_xor(s, off, 64);

    float inv = 1.0f / s;
    float4 o;
    o.x = e0 * inv;
    o.y = e1 * inv;
    o.z = e2 * inv;
    o.w = e3 * inv;
    *(float4*)&rp[lane << 2] = o;
}

// ---------------- Attended: out[b] = attn[b] (256x256) @ v[b] (256x768) ----------------
// BM=64, BN=32, BK=16, 256 thr, 4x2 micro, prefetch. grid (24,4,4)=384 blocks.
__global__ __launch_bounds__(256) void attended_gemm_kernel(
    const float* __restrict__ attn, const float* __restrict__ vs,
    float* __restrict__ out)
{
    const int b = blockIdx.z;
    const float* A = attn + (size_t)b * SLQ * SLK;
    const float* Bm = vs + (size_t)b * SLK * DD;
    float* C = out + (size_t)b * SLQ * DD;

    __shared__ __align__(16) float As[16][68]; // [k][m]
    __shared__ __align__(16) float Bs[16][32]; // [k][n]

    const int tid = threadIdx.x;
    const int tx = tid & 15;       // col-group (2 cols)
    const int ty = tid >> 4;       // row-group (4 rows)
    const int row0 = blockIdx.y * 64;
    const int col0 = blockIdx.x * 32;
    const int a_r = tid >> 2;
    const int a_k = (tid & 3) << 2;
    const int b_r = tid >> 3;          // 0..15 (tid<128)
    const int b_c = (tid & 7) << 2;    // 0..28

    const float* Aptr = A + (size_t)(row0 + a_r) * SLK + a_k;
    const float* Bptr = Bm + (size_t)b_r * DD + col0 + b_c;

    float4 av = *(const float4*)Aptr;
    float4 bv;
    if (tid < 128) bv = *(const float4*)Bptr;

    float acc[4][2] = {};

    for (int k0 = 0; k0 < SLK; k0 += 16) {
        __syncthreads();
        As[a_k + 0][a_r] = av.x;
        As[a_k + 1][a_r] = av.y;
        As[a_k + 2][a_r] = av.z;
        As[a_k + 3][a_r] = av.w;
        if (tid < 128) *(float4*)&Bs[b_r][b_c] = bv;
        __syncthreads();
        if (k0 + 16 < SLK) {
            av = *(const float4*)(Aptr + k0 + 16);
            if (tid < 128) bv = *(const float4*)(Bptr + (size_t)(k0 + 16) * DD);
        }
#pragma unroll
        for (int kk = 0; kk < 16; ++kk) {
            float4 a = *(const float4*)&As[kk][ty << 2];
            float2 bb = *(const float2*)&Bs[kk][tx << 1];
            acc[0][0] = fmaf(a.x, bb.x, acc[0][0]);
            acc[0][1] = fmaf(a.x, bb.y, acc[0][1]);
            acc[1][0] = fmaf(a.y, bb.x, acc[1][0]);
            acc[1][1] = fmaf(a.y, bb.y, acc[1][1]);
            acc[2][0] = fmaf(a.z, bb.x, acc[2][0]);
            acc[2][1] = fmaf(a.z, bb.y, acc[2][1]);
            acc[3][0] = fmaf(a.w, bb.x, acc[3][0]);
            acc[3][1] = fmaf(a.w, bb.y, acc[3][1]);
        }
    }

#pragma unroll
    for (int i = 0; i < 4; ++i) {
        float2 o;
        o.x = acc[i][0];
        o.y = acc[i][1];
        *(float2*)&C[(size_t)(row0 + (ty << 2) + i) * DD + col0 + (tx << 1)] = o;
    }
}

extern "C" void kernel_launch(void* const* d_in, const int* in_sizes, int n_in,
                              void* d_out, int out_size, void* d_ws, size_t ws_size,
                              hipStream_t stream)
{
    (void)in_sizes; (void)n_in; (void)out_size; (void)ws_size;

    const float* query = (const float*)d_in[0];
    const float* key   = (const float*)d_in[1];
    const float* value = (const float*)d_in[2];
    const float* Wq = (const float*)d_in[3];
    const float* bq = (const float*)d_in[4];
    const float* Wk = (const float*)d_in[5];
    const float* bk = (const float*)d_in[6];
    const float* Wv = (const float*)d_in[7];
    const float* bv = (const float*)d_in[8];
    const float* Ws = (const float*)d_in[9];
    // d_in[10] (bs) is a softmax-invariant shift: unused.

    float* ws = (float*)d_ws;
    float* eq = ws;                       // [4,256,768] exp2 of scaled q-proj
    float* ek = eq + NB * SLQ * DD;       // [4,256,768] exp2 of scaled k-proj
    float* vs = ek + NB * SLK * DD;       // [4,256,768] v-proj

    float* out = (float*)d_out;
    float* attended = out;                // [4,256,768]
    float* attnw = out + NB * SLQ * DD;   // [4,256,256]: logits -> softmax in-place

    qkv_gemm_kernel<<<dim3(DD / 64, (NB * SLQ) / 64, 3), 256, 0, stream>>>(
        query, key, value, Wq, bq, Wk, bk, Wv, bv, eq, ek, vs);
    scores_kernel<<<dim3(SLK / 64, SLQ / 4, NB), 256, 0, stream>>>(eq, ek, Ws, attnw);
    softmax_kernel<<<dim3((NB * SLQ) / 4), 256, 0, stream>>>(attnw);
    attended_gemm_kernel<<<dim3(DD / 32, SLQ / 64, NB), 256, 0, stream>>>(attnw, vs, attended);
}

// Round 3
// 157.841 us; speedup vs baseline: 1.3702x; 1.2094x over previous
//
#include <hip/hip_runtime.h>

#define NB 4
#define SLQ 256
#define SLK 256
#define DD 768

// tanh(x) = 1 - 2/(1+e^{2x});  e^{2(q+k)} = exp2(q*2log2e)*exp2(k*2log2e)
// computed once per projection element. Softmax-invariant terms dropped.
#define TWO_LOG2E 2.8853900817779268f
#define LOG2E 1.4426950408889634f

typedef _Float16 f16x4 __attribute__((ext_vector_type(4)));
typedef _Float16 f16x8 __attribute__((ext_vector_type(8)));
typedef float f32x4 __attribute__((ext_vector_type(4)));

__device__ __forceinline__ float fexp2(float x) { return __builtin_amdgcn_exp2f(x); }
__device__ __forceinline__ float frcp(float x) { return __builtin_amdgcn_rcpf(x); }

// LDS row stride (halves) for MFMA operand tiles: 40*2B=80B (16B-aligned,
// bank shift 20/row -> worst 4-way on frag reads, mostly 2-way).
#define LSTR 40

// ---------------- QKV projection via fp16 MFMA ----------------
// C = A @ W + bias. A:[1024x768] fp32, W:[768x768] fp32 ([in,out]).
// z=0 -> eq fp32 = exp2(q*2log2e); z=1 -> ekh half = exp2(k*2log2e); z=2 -> vsh half = v.
// 64x64 tile, BK=32, 256 thr = 4 waves (2x2 of 32x32), mfma_f32_16x16x32_f16.
__global__ __launch_bounds__(256) void qkv_f16_kernel(
    const float* __restrict__ query, const float* __restrict__ key_in,
    const float* __restrict__ value, const float* __restrict__ Wq,
    const float* __restrict__ bq, const float* __restrict__ Wk,
    const float* __restrict__ bk, const float* __restrict__ Wv,
    const float* __restrict__ bv, float* __restrict__ eq,
    _Float16* __restrict__ ekh, _Float16* __restrict__ vsh)
{
    const int z = blockIdx.z;
    const float* A = (z == 0) ? query : (z == 1) ? key_in : value;
    const float* W = (z == 0) ? Wq : (z == 1) ? Wk : Wv;
    const float* bias = (z == 0) ? bq : (z == 1) ? bk : bv;

    __shared__ _Float16 Ah[64 * LSTR]; // [m][k] halves
    __shared__ _Float16 Bt[64 * LSTR]; // [n][k] halves (W transposed)

    const int tid = threadIdx.x;
    const int lane = tid & 63;
    const int wid = tid >> 6;
    const int wr = wid >> 1;   // wave row (0..1)
    const int wc = wid & 1;    // wave col (0..1)
    const int row0 = blockIdx.y * 64;
    const int col0 = blockIdx.x * 64;

    // A staging map: 64 rows x 8 float4 = 512 float4, 2 per thread
    const int ar = tid >> 3;          // row 0..31 (+32 on j=1? no: fidx up to 511)
    const int ac4 = (tid & 7) << 2;   // col 0..28
    // B staging map: 32 k-rows x 16 float4 = 512, 2 per thread
    const int bk_ = tid >> 4;         // k 0..15 (+16 on second)
    const int bn4 = (tid & 15) << 2;  // n 0..60

    float4 pa0, pa1, pb0, pb1;
    {
        pa0 = *(const float4*)&A[(size_t)(row0 + ar) * DD + ac4];
        pa1 = *(const float4*)&A[(size_t)(row0 + ar + 32) * DD + ac4];
        pb0 = *(const float4*)&W[(size_t)bk_ * DD + col0 + bn4];
        pb1 = *(const float4*)&W[(size_t)(bk_ + 16) * DD + col0 + bn4];
    }

    f32x4 acc[2][2] = {};
    const int kj = (lane >> 4) << 3;        // k-offset of this lane's frag
    const int fr = lane & 15;               // frag row/col

    for (int s = 0; s < DD / 32; ++s) {
        __syncthreads();
        {
            f16x4 h;
            h[0] = (_Float16)pa0.x; h[1] = (_Float16)pa0.y;
            h[2] = (_Float16)pa0.z; h[3] = (_Float16)pa0.w;
            *(f16x4*)&Ah[ar * LSTR + ac4] = h;
            h[0] = (_Float16)pa1.x; h[1] = (_Float16)pa1.y;
            h[2] = (_Float16)pa1.z; h[3] = (_Float16)pa1.w;
            *(f16x4*)&Ah[(ar + 32) * LSTR + ac4] = h;
            Bt[(bn4 + 0) * LSTR + bk_] = (_Float16)pb0.x;
            Bt[(bn4 + 1) * LSTR + bk_] = (_Float16)pb0.y;
            Bt[(bn4 + 2) * LSTR + bk_] = (_Float16)pb0.z;
            Bt[(bn4 + 3) * LSTR + bk_] = (_Float16)pb0.w;
            Bt[(bn4 + 0) * LSTR + bk_ + 16] = (_Float16)pb1.x;
            Bt[(bn4 + 1) * LSTR + bk_ + 16] = (_Float16)pb1.y;
            Bt[(bn4 + 2) * LSTR + bk_ + 16] = (_Float16)pb1.z;
            Bt[(bn4 + 3) * LSTR + bk_ + 16] = (_Float16)pb1.w;
        }
        __syncthreads();
        if (s + 1 < DD / 32) {
            const int ks = (s + 1) * 32;
            pa0 = *(const float4*)&A[(size_t)(row0 + ar) * DD + ks + ac4];
            pa1 = *(const float4*)&A[(size_t)(row0 + ar + 32) * DD + ks + ac4];
            pb0 = *(const float4*)&W[(size_t)(ks + bk_) * DD + col0 + bn4];
            pb1 = *(const float4*)&W[(size_t)(ks + bk_ + 16) * DD + col0 + bn4];
        }
        f16x8 af0 = *(const f16x8*)&Ah[(wr * 32 + fr) * LSTR + kj];
        f16x8 af1 = *(const f16x8*)&Ah[(wr * 32 + 16 + fr) * LSTR + kj];
        f16x8 bf0 = *(const f16x8*)&Bt[(wc * 32 + fr) * LSTR + kj];
        f16x8 bf1 = *(const f16x8*)&Bt[(wc * 32 + 16 + fr) * LSTR + kj];
        acc[0][0] = __builtin_amdgcn_mfma_f32_16x16x32_f16(af0, bf0, acc[0][0], 0, 0, 0);
        acc[0][1] = __builtin_amdgcn_mfma_f32_16x16x32_f16(af0, bf1, acc[0][1], 0, 0, 0);
        acc[1][0] = __builtin_amdgcn_mfma_f32_16x16x32_f16(af1, bf0, acc[1][0], 0, 0, 0);
        acc[1][1] = __builtin_amdgcn_mfma_f32_16x16x32_f16(af1, bf1, acc[1][1], 0, 0, 0);
    }

    // C/D layout: col = lane&15, row = (lane>>4)*4 + reg  [m89 verified]
    const int colb = col0 + wc * 32 + fr;
    const int rowb = row0 + wr * 32 + ((lane >> 4) << 2);
#pragma unroll
    for (int mf = 0; mf < 2; ++mf) {
#pragma unroll
        for (int nf = 0; nf < 2; ++nf) {
            const int col = colb + nf * 16;
            const float bv = bias[col];
#pragma unroll
            for (int r = 0; r < 4; ++r) {
                const int row = rowb + mf * 16 + r;
                const float val = acc[mf][nf][r] + bv;
                if (z == 0) {
                    eq[(size_t)row * DD + col] = fexp2(fminf(val * TWO_LOG2E, 15.0f));
                } else if (z == 1) {
                    ekh[(size_t)row * DD + col] =
                        (_Float16)fexp2(fminf(val * TWO_LOG2E, 15.0f));
                } else {
                    vsh[(size_t)row * DD + col] = (_Float16)val;
                }
            }
        }
    }
}

// ---------------- Scores: pure-register / scalar-load version ----------------
// logits[b,q,k] = -2 * sum_d Ws_d * rcp(1 + Eq[q,d]*Ek[k,d])
// Each wave: 2 q-rows x 64 k (lane = k, k-row streamed from L2 into regs;
// q and Ws are wave-uniform -> scalar loads). No LDS, no barriers.
__global__ __launch_bounds__(256) void scores_kernel(
    const float* __restrict__ Eq, const _Float16* __restrict__ Ekh,
    const float* __restrict__ Ws, float* __restrict__ logits)
{
    const int b = blockIdx.z;
    const int k0 = blockIdx.x * 64;
    const int q0 = blockIdx.y * 8;
    const int lane = threadIdx.x & 63;
    const int wid = __builtin_amdgcn_readfirstlane((int)(threadIdx.x >> 6));
    const int q = q0 + (wid << 1);

    const _Float16* kr = Ekh + (size_t)(b * SLK + k0 + lane) * DD;
    const float* qp0 = Eq + (size_t)(b * SLQ + q) * DD;
    const float* qp1 = qp0 + DD;

    float acc0 = 0.f, acc1 = 0.f;

    f16x4 e[4], en[4];
    float g0[16], g1[16], w[16], g0n[16], g1n[16], wn[16];
#pragma unroll
    for (int j = 0; j < 4; ++j) e[j] = *(const f16x4*)(kr + j * 4);
#pragma unroll
    for (int j = 0; j < 16; ++j) { g0[j] = qp0[j]; g1[j] = qp1[j]; w[j] = Ws[j]; }

    for (int c = 0; c < DD / 16; ++c) {
        const int dn = (c + 1) * 16;
        if (c + 1 < DD / 16) {
#pragma unroll
            for (int j = 0; j < 4; ++j) en[j] = *(const f16x4*)(kr + dn + j * 4);
#pragma unroll
            for (int j = 0; j < 16; ++j) {
                g0n[j] = qp0[dn + j]; g1n[j] = qp1[dn + j]; wn[j] = Ws[dn + j];
            }
        }
#pragma unroll
        for (int j = 0; j < 16; ++j) {
            const float ev = (float)e[j >> 2][j & 3];
            const float r0 = frcp(fmaf(g0[j], ev, 1.0f));
            const float r1 = frcp(fmaf(g1[j], ev, 1.0f));
            acc0 = fmaf(w[j], r0, acc0);
            acc1 = fmaf(w[j], r1, acc1);
        }
#pragma unroll
        for (int j = 0; j < 4; ++j) e[j] = en[j];
#pragma unroll
        for (int j = 0; j < 16; ++j) { g0[j] = g0n[j]; g1[j] = g1n[j]; w[j] = wn[j]; }
    }

    logits[(size_t)(b * SLQ + q) * SLK + k0 + lane] = -2.0f * acc0;
    logits[(size_t)(b * SLQ + q + 1) * SLK + k0 + lane] = -2.0f * acc1;
}

// ---------------- Softmax over k (in-place fp32) + half copy for attended ----------------
__global__ __launch_bounds__(256) void softmax_kernel(float* __restrict__ attn,
                                                      _Float16* __restrict__ phalf)
{
    const int lane = threadIdx.x & 63;
    const int wave = threadIdx.x >> 6;
    const int row = blockIdx.x * 4 + wave;
    float* rp = attn + (size_t)row * SLK;

    float4 x = *(const float4*)&rp[lane << 2];
    float m = fmaxf(fmaxf(x.x, x.y), fmaxf(x.z, x.w));
#pragma unroll
    for (int off = 32; off; off >>= 1) m = fmaxf(m, __shfl_xor(m, off, 64));

    float e0 = fexp2((x.x - m) * LOG2E);
    float e1 = fexp2((x.y - m) * LOG2E);
    float e2 = fexp2((x.z - m) * LOG2E);
    float e3 = fexp2((x.w - m) * LOG2E);
    float s = (e0 + e1) + (e2 + e3);
#pragma unroll
    for (int off = 32; off; off >>= 1) s += __shfl_xor(s, off, 64);

    const float inv = 1.0f / s;
    float4 o;
    o.x = e0 * inv; o.y = e1 * inv; o.z = e2 * inv; o.w = e3 * inv;
    *(float4*)&rp[lane << 2] = o;

    f16x4 h;
    h[0] = (_Float16)o.x; h[1] = (_Float16)o.y;
    h[2] = (_Float16)o.z; h[3] = (_Float16)o.w;
    *(f16x4*)&phalf[(size_t)row * SLK + (lane << 2)] = h;
}

// ---------------- Attended: out[b] = P[b] (256x256) @ V[b] (256x768), fp16 MFMA ----------------
__global__ __launch_bounds__(256) void attended_f16_kernel(
    const _Float16* __restrict__ phalf, const _Float16* __restrict__ vsh,
    float* __restrict__ out)
{
    const int b = blockIdx.z;
    const _Float16* P = phalf + (size_t)b * SLQ * SLK;
    const _Float16* V = vsh + (size_t)b * SLK * DD;
    float* C = out + (size_t)b * SLQ * DD;

    __shared__ _Float16 Ah[64 * LSTR]; // [m][k]
    __shared__ _Float16 Bt[64 * LSTR]; // [n][k]

    const int tid = threadIdx.x;
    const int lane = tid & 63;
    const int wid = tid >> 6;
    const int wr = wid >> 1;
    const int wc = wid & 1;
    const int row0 = blockIdx.y * 64;
    const int col0 = blockIdx.x * 64;

    // A staging: 64 rows x 32 k halves = 256 f16x8, 1 per thread
    const int ar = tid >> 2;          // 0..63
    const int ac8 = (tid & 3) << 3;   // 0,8,16,24
    // B staging: 32 k x 64 n halves = 256 f16x8, 1 per thread
    const int bk_ = tid >> 3;         // 0..31
    const int bn8 = (tid & 7) << 3;   // 0..56

    f16x8 pa = *(const f16x8*)&P[(size_t)(row0 + ar) * SLK + ac8];
    f16x8 pb = *(const f16x8*)&V[(size_t)bk_ * DD + col0 + bn8];

    f32x4 acc[2][2] = {};
    const int kj = (lane >> 4) << 3;
    const int fr = lane & 15;

    for (int s = 0; s < SLK / 32; ++s) {
        __syncthreads();
        *(f16x8*)&Ah[ar * LSTR + ac8] = pa;
#pragma unroll
        for (int i = 0; i < 8; ++i) Bt[(bn8 + i) * LSTR + bk_] = pb[i];
        __syncthreads();
        if (s + 1 < SLK / 32) {
            const int ks = (s + 1) * 32;
            pa = *(const f16x8*)&P[(size_t)(row0 + ar) * SLK + ks + ac8];
            pb = *(const f16x8*)&V[(size_t)(ks + bk_) * DD + col0 + bn8];
        }
        f16x8 af0 = *(const f16x8*)&Ah[(wr * 32 + fr) * LSTR + kj];
        f16x8 af1 = *(const f16x8*)&Ah[(wr * 32 + 16 + fr) * LSTR + kj];
        f16x8 bf0 = *(const f16x8*)&Bt[(wc * 32 + fr) * LSTR + kj];
        f16x8 bf1 = *(const f16x8*)&Bt[(wc * 32 + 16 + fr) * LSTR + kj];
        acc[0][0] = __builtin_amdgcn_mfma_f32_16x16x32_f16(af0, bf0, acc[0][0], 0, 0, 0);
        acc[0][1] = __builtin_amdgcn_mfma_f32_16x16x32_f16(af0, bf1, acc[0][1], 0, 0, 0);
        acc[1][0] = __builtin_amdgcn_mfma_f32_16x16x32_f16(af1, bf0, acc[1][0], 0, 0, 0);
        acc[1][1] = __builtin_amdgcn_mfma_f32_16x16x32_f16(af1, bf1, acc[1][1], 0, 0, 0);
    }

    const int colb = col0 + wc * 32 + fr;
    const int rowb = row0 + wr * 32 + ((lane >> 4) << 2);
#pragma unroll
    for (int mf = 0; mf < 2; ++mf)
#pragma unroll
        for (int nf = 0; nf < 2; ++nf)
#pragma unroll
            for (int r = 0; r < 4; ++r)
                C[(size_t)(rowb + mf * 16 + r) * DD + colb + nf * 16] = acc[mf][nf][r];
}

extern "C" void kernel_launch(void* const* d_in, const int* in_sizes, int n_in,
                              void* d_out, int out_size, void* d_ws, size_t ws_size,
                              hipStream_t stream)
{
    (void)in_sizes; (void)n_in; (void)out_size; (void)ws_size;

    const float* query = (const float*)d_in[0];
    const float* key   = (const float*)d_in[1];
    const float* value = (const float*)d_in[2];
    const float* Wq = (const float*)d_in[3];
    const float* bq = (const float*)d_in[4];
    const float* Wk = (const float*)d_in[5];
    const float* bk = (const float*)d_in[6];
    const float* Wv = (const float*)d_in[7];
    const float* bv = (const float*)d_in[8];
    const float* Ws = (const float*)d_in[9];
    // d_in[10] (bs): softmax-invariant shift, unused.

    const size_t NE = (size_t)NB * SLQ * DD;   // 786432
    float* eq = (float*)d_ws;                  // fp32 [NE]
    _Float16* ekh = (_Float16*)(eq + NE);      // half [NE]
    _Float16* vsh = ekh + NE;                  // half [NE]
    _Float16* phalf = vsh + NE;                // half [4*256*256]

    float* out = (float*)d_out;
    float* attended = out;                     // [4,256,768]
    float* attnw = out + NE;                   // [4,256,256] logits -> softmax in-place

    qkv_f16_kernel<<<dim3(DD / 64, (NB * SLQ) / 64, 3), 256, 0, stream>>>(
        query, key, value, Wq, bq, Wk, bk, Wv, bv, eq, ekh, vsh);
    scores_kernel<<<dim3(SLK / 64, SLQ / 8, NB), 256, 0, stream>>>(eq, ekh, Ws, attnw);
    softmax_kernel<<<dim3((NB * SLQ) / 4), 256, 0, stream>>>(attnw, phalf);
    attended_f16_kernel<<<dim3(DD / 64, SLQ / 64, NB), 256, 0, stream>>>(phalf, vsh, attended);
}